// Round 7
// baseline (122.737 us; speedup 1.0000x reference)
//
#include <hip/hip_runtime.h>

#define HH 479
#define WW 639
#define BATCH 8
#define CT 12                       // column tiles: 56 output cols each
#define RBAND 60                    // 8-row bands
#define NBLK (CT * RBAND * BATCH)   // 5760 wave-slots
#define GY 15                       // grid.y: 4 bands per block

// R17: R16's barrier-free marching window + 2x TLP. R16 counters isolated
// the binder: VALUBusy 45%, Occupancy 22% (2880 waves = 2.8/SIMD), FETCH
// near-ideal, 0 conflicts, 0 LDS -> pure wave starvation. Band height
// 16 -> 8 (+4.7% total VALU work from warmup redundancy) doubles waves to
// 5760 = 5.6/SIMD; packed 4 independent waves per 256-thread block (NO
// barrier, threadIdx.y = sub-band) to dodge per-CU workgroup-count limits.
// Each wave stores its own acc slot. Shorter slide chains also cut the fp32
// drift seen in R16 (absmax 3.9e-3).
// Structure (R16): vertical 8-row column sums in registers (slide-by-1 down
// the band; L1 absorbs re-reads), horizontal box-8 of 9 absolute-weighted
// fields {S1,Sb,Sbb,T1,Tb,aS1,aSb,aT1,a2S1} via 3-step ds_bpermute
// butterfly (lane+1,+2,+4) on the DS pipe. One wave = 64 cols (56 outputs
// + 8 halo). Solve (f32, R5-validated): centered A_hat + Sherman-Morrison
// => same unit normal as (M+eps I)^-1 s. Retirement: per-wave STORE into
// acc[slot] (no memset), tiny finalize. (R2/R3: readback poisons it.)

__device__ __forceinline__ float box8(float x, int a1, int a2, int a4)
{
    // sum over lanes [lane, lane+7]; lanes >= 56 produce garbage (masked)
    float t = x + __int_as_float(
        __builtin_amdgcn_ds_bpermute(a1, __float_as_int(x)));
    t += __int_as_float(__builtin_amdgcn_ds_bpermute(a2, __float_as_int(t)));
    t += __int_as_float(__builtin_amdgcn_ds_bpermute(a4, __float_as_int(t)));
    return t;
}

__device__ __forceinline__ void solve_normal(
    float xx, float xy, float xz, float yy, float yz, float zz,
    float xs, float ys, float zs,
    float a_c, float b_c, float d0,
    float* nx, float* ny, float* nz)
{
    const float EPSV = 1e-6f;
    const float inv64 = 1.0f / 64.0f;
    float hx = xs * inv64, hy = ys * inv64, hz = zs * inv64;
    float cxx = fmaf(-hx, xs, xx) + EPSV;
    float cxy = fmaf(-hx, ys, xy);
    float cxz = fmaf(-hx, zs, xz);
    float cyy = fmaf(-hy, ys, yy) + EPSV;
    float cyz = fmaf(-hy, zs, yz);
    float czz = fmaf(-hz, zs, zz) + EPSV;
    float c00 = fmaf(cyy, czz, -cyz * cyz);
    float c01 = fmaf(cxz, cyz, -cxy * czz);
    float c02 = fmaf(cxy, cyz, -cxz * cyy);
    float c11 = fmaf(cxx, czz, -cxz * cxz);
    float c12 = fmaf(cxy, cxz, -cxx * cyz);
    float c22 = fmaf(cxx, cyy, -cxy * cxy);
    float m0 = fmaf(c00, xs, fmaf(c01, ys, c02 * zs));
    float m1 = fmaf(c01, xs, fmaf(c11, ys, c12 * zs));
    float m2 = fmaf(c02, xs, fmaf(c12, ys, c22 * zs));
    float g  = fmaf(m0, a_c, fmaf(m1, b_c, m2));   // sign of dot(n, xyz), d0>0
    float inv = rsqrtf(fmaf(m0, m0, fmaf(m1, m1, m2 * m2)));
    if (g > 0.0f) inv = -inv;
    if (!(d0 > 0.0f)) inv = 0.0f;                  // where(depth>0, n, 0)
    *nx = m0 * inv; *ny = m1 * inv; *nz = m2 * inv;
}

__global__ __launch_bounds__(256, 6)
void ppal_main(const float* __restrict__ pred, const float* __restrict__ gt,
               double* __restrict__ acc)
{
    const int lane = threadIdx.x;            // 0..63
    const int wy   = threadIdx.y;            // 0..3 (independent sub-band)
    const int j0 = blockIdx.x * 56;
    const int band = blockIdx.y * 4 + wy;    // 0..59
    const int r0 = band * 8;
    const int b  = blockIdx.z;

    const float invFX = 1.0f / 518.857f;
    const float invFY = 1.0f / 519.469f;

    const float* __restrict__ pA = pred + (size_t)b * (HH * WW);
    const float* __restrict__ pB = gt   + (size_t)b * (HH * WW);

    const int c = j0 - 4 + lane;             // owned window column
    const int j = j0 + lane;                 // owned output column
    const bool col_ok = (c >= 0) && (c < WW);
    const bool pix_ok = (lane < 56) && (j < WW);
    const float a  = ((float)c - 319.5f) * invFX;   // column x-weight
    const float a2 = a * a;
    const float ap = ((float)j - 319.5f) * invFX;   // pixel x-weight
    const int ba1 = ((lane + 1) & 63) << 2;
    const int ba2 = ((lane + 2) & 63) << 2;
    const int ba4 = ((lane + 4) & 63) << 2;

    // vertical 8-row sliding sums for own column, both inputs
    float S1A = 0.f, SbA = 0.f, SbbA = 0.f, T1A = 0.f, TbA = 0.f;
    float S1B = 0.f, SbB = 0.f, SbbB = 0.f, T1B = 0.f, TbB = 0.f;

    // ---- warmup: rows r0-4 .. r0+3 (zero-padded OOB) ----
    int off = (r0 - 4) * WW + c;
#pragma unroll
    for (int w = 0; w < 8; ++w) {
        int r = r0 - 4 + w;                  // r <= r0+3 <= 475 < HH always
        bool ok = col_ok && (r >= 0);
        int o = ok ? off : 0;
        float dA = pA[o]; dA = ok ? dA : 0.f;
        float dB = pB[o]; dB = ok ? dB : 0.f;
        float bv = ((float)r - 239.5f) * invFY;
        float bdA = bv * dA, bdB = bv * dB;
        T1A += dA;  TbA += bdA;
        S1A = fmaf(dA,  dA,  S1A);
        SbA = fmaf(bdA, dA,  SbA);
        SbbA = fmaf(bdA, bdA, SbbA);
        T1B += dB;  TbB += bdB;
        S1B = fmaf(dB,  dB,  S1B);
        SbB = fmaf(bdB, dB,  SbB);
        SbbB = fmaf(bdB, bdB, SbbB);
        off += WW;
    }

    // ---- march 8 output rows ----
    float contrib = 0.f;
    int off_new = (r0 + 4) * WW + c;
    int off_old = (r0 - 4) * WW + c;
    int off_ctr = r0 * WW + j;

    for (int s = 0; s < 8; ++s) {
        const int i = r0 + s;
        const bool row_ok = (i < HH);

        // ---- emit pixel (i, j): V holds rows i-4..i+3 ----
        {
            const bool okc = row_ok && pix_ok;
            int o = okc ? off_ctr : 0;
            float d0A = pA[o]; d0A = okc ? d0A : 0.f;
            float d0B = pB[o]; d0B = okc ? d0B : 0.f;
            float bc = ((float)i - 239.5f) * invFY;

            // input A: 9 horizontal box-8 sums -> solve
            float hS1  = box8(S1A,      ba1, ba2, ba4);
            float hSb  = box8(SbA,      ba1, ba2, ba4);
            float hSbb = box8(SbbA,     ba1, ba2, ba4);
            float hT1  = box8(T1A,      ba1, ba2, ba4);
            float hTb  = box8(TbA,      ba1, ba2, ba4);
            float haS1 = box8(a * S1A,  ba1, ba2, ba4);
            float haSb = box8(a * SbA,  ba1, ba2, ba4);
            float haT1 = box8(a * T1A,  ba1, ba2, ba4);
            float ha2S1= box8(a2 * S1A, ba1, ba2, ba4);
            float nA[3];
            solve_normal(ha2S1, haSb, haS1, hSbb, hSb, hS1, haT1, hTb, hT1,
                         ap, bc, d0A, &nA[0], &nA[1], &nA[2]);

            // input B
            float gS1  = box8(S1B,      ba1, ba2, ba4);
            float gSb  = box8(SbB,      ba1, ba2, ba4);
            float gSbb = box8(SbbB,     ba1, ba2, ba4);
            float gT1  = box8(T1B,      ba1, ba2, ba4);
            float gTb  = box8(TbB,      ba1, ba2, ba4);
            float gaS1 = box8(a * S1B,  ba1, ba2, ba4);
            float gaSb = box8(a * SbB,  ba1, ba2, ba4);
            float gaT1 = box8(a * T1B,  ba1, ba2, ba4);
            float ga2S1= box8(a2 * S1B, ba1, ba2, ba4);
            float nB[3];
            solve_normal(ga2S1, gaSb, gaS1, gSbb, gSb, gS1, gaT1, gTb, gT1,
                         ap, bc, d0B, &nB[0], &nB[1], &nB[2]);

            float cp = fabsf(nA[0] - nB[0]) + fabsf(nA[1] - nB[1])
                     + fabsf(nA[2] - nB[2]);
            contrib += okc ? cp : 0.f;
        }

        // ---- slide: row i-4 leaves, row i+4 enters ----
        {
            const bool okn = col_ok && (i + 4 < HH);
            const bool oko = col_ok && (i - 4 >= 0);
            int on = okn ? off_new : 0;
            int oo = oko ? off_old : 0;
            float dnA = pA[on]; dnA = okn ? dnA : 0.f;
            float dnB = pB[on]; dnB = okn ? dnB : 0.f;
            float doA = pA[oo]; doA = oko ? doA : 0.f;
            float doB = pB[oo]; doB = oko ? doB : 0.f;
            float bn = ((float)(i + 4) - 239.5f) * invFY;
            float bo = ((float)(i - 4) - 239.5f) * invFY;
            float bdnA = bn * dnA, bdoA = bo * doA;
            float bdnB = bn * dnB, bdoB = bo * doB;
            T1A += dnA - doA;   TbA += bdnA - bdoA;
            S1A += fmaf(dnA,  dnA,  -doA  * doA);
            SbA += fmaf(bdnA, dnA,  -bdoA * doA);
            SbbA += fmaf(bdnA, bdnA, -bdoA * bdoA);
            T1B += dnB - doB;   TbB += bdnB - bdoB;
            S1B += fmaf(dnB,  dnB,  -doB  * doB);
            SbB += fmaf(bdnB, dnB,  -bdoB * doB);
            SbbB += fmaf(bdnB, bdnB, -bdoB * bdoB);
            off_new += WW; off_old += WW; off_ctr += WW;
        }
    }

    // ---- wave reduce -> ONE plain STORE per wave (no cross-wave sync) ----
    float v = contrib;
#pragma unroll
    for (int o = 32; o > 0; o >>= 1) v += __shfl_down(v, o, 64);
    if (lane == 0) {
        int slot = blockIdx.x + CT * band + (CT * RBAND) * blockIdx.z;
        acc[slot] = (double)v;   // unique slot, written every launch
    }
}

__global__ void ppal_finalize(const double* __restrict__ acc, float* __restrict__ out)
{
    int tid = threadIdx.x;             // 256 threads, one block
    double v = 0.0;
    for (int s = tid; s < NBLK; s += 256) v += acc[s];
#pragma unroll
    for (int off = 32; off > 0; off >>= 1) v += __shfl_down(v, off, 64);
    __shared__ double wsum[4];
    int wid = tid >> 6, lane = tid & 63;
    if (lane == 0) wsum[wid] = v;
    __syncthreads();
    if (tid == 0)
        out[0] = (float)((wsum[0] + wsum[1] + wsum[2] + wsum[3])
                         * (1.0 / 7345944.0));  // mean over B*3*H*W
}

extern "C" void kernel_launch(void* const* d_in, const int* in_sizes, int n_in,
                              void* d_out, int out_size, void* d_ws, size_t ws_size,
                              hipStream_t stream)
{
    const float* pred = (const float*)d_in[0];
    const float* gt   = (const float*)d_in[1];
    float* out  = (float*)d_out;
    double* acc = (double*)d_ws;

    dim3 grid(CT, GY, BATCH);          // 1440 blocks x 4 independent waves
    dim3 block(64, 4);
    ppal_main<<<grid, block, 0, stream>>>(pred, gt, acc);
    ppal_finalize<<<1, 256, 0, stream>>>(acc, out);
}

// Round 8
// 107.355 us; speedup vs baseline: 1.1433x; 1.1433x over previous
//
#include <hip/hip_runtime.h>

#define HH 479
#define WW 639
#define BATCH 8
#define CT 12                       // column tiles: 56 output cols each
#define RBAND 60                    // 8-row bands
#define NBLK (CT * RBAND * BATCH)   // 5760 wave-slots
#define GY 30                       // grid.y: 2 bands per block

// R18: R17's TLP (8-row bands, 5760 waves) + R16's register allocation.
// R17 post-mortem: occupancy doubled as designed (22->48.6%) but
// launch_bounds(256,6) squeezed VGPR 52->40 -> spills: WRITE_SIZE 90KB ->
// 72.9MB/dispatch (scratch traffic smoking gun), FETCH 27->81MB, wall
// 48->59us. Fix: pack only 2 waves per 128-thread block (2880 blocks,
// ~11/CU, under any per-CU WG cap) with RELAXED launch_bounds(128,2)
// (VGPR cap 256) so the allocator re-picks ~52 VGPR spill-free as in R16.
// Structure (R16): barrier-free marching window. Vertical 8-row column
// sums in registers (slide-by-1 down the band; L1 absorbs re-reads),
// horizontal box-8 of 9 absolute-weighted fields {S1,Sb,Sbb,T1,Tb,aS1,
// aSb,aT1,a2S1} via 3-step ds_bpermute butterfly (lane+1,+2,+4) on the DS
// pipe. One wave = 64 cols (56 outputs + 8 halo) x 8 rows; no LDS, no
// barriers, waves fully independent (threadIdx.y = sub-band). Solve (f32,
// R5-validated): centered A_hat + Sherman-Morrison => same unit normal as
// (M+eps I)^-1 s. Retirement: per-wave STORE into acc[slot] (no memset),
// tiny finalize. (R2/R3: fence+counter readback poisons retirement.)

__device__ __forceinline__ float box8(float x, int a1, int a2, int a4)
{
    // sum over lanes [lane, lane+7]; lanes >= 56 produce garbage (masked)
    float t = x + __int_as_float(
        __builtin_amdgcn_ds_bpermute(a1, __float_as_int(x)));
    t += __int_as_float(__builtin_amdgcn_ds_bpermute(a2, __float_as_int(t)));
    t += __int_as_float(__builtin_amdgcn_ds_bpermute(a4, __float_as_int(t)));
    return t;
}

__device__ __forceinline__ void solve_normal(
    float xx, float xy, float xz, float yy, float yz, float zz,
    float xs, float ys, float zs,
    float a_c, float b_c, float d0,
    float* nx, float* ny, float* nz)
{
    const float EPSV = 1e-6f;
    const float inv64 = 1.0f / 64.0f;
    float hx = xs * inv64, hy = ys * inv64, hz = zs * inv64;
    float cxx = fmaf(-hx, xs, xx) + EPSV;
    float cxy = fmaf(-hx, ys, xy);
    float cxz = fmaf(-hx, zs, xz);
    float cyy = fmaf(-hy, ys, yy) + EPSV;
    float cyz = fmaf(-hy, zs, yz);
    float czz = fmaf(-hz, zs, zz) + EPSV;
    float c00 = fmaf(cyy, czz, -cyz * cyz);
    float c01 = fmaf(cxz, cyz, -cxy * czz);
    float c02 = fmaf(cxy, cyz, -cxz * cyy);
    float c11 = fmaf(cxx, czz, -cxz * cxz);
    float c12 = fmaf(cxy, cxz, -cxx * cyz);
    float c22 = fmaf(cxx, cyy, -cxy * cxy);
    float m0 = fmaf(c00, xs, fmaf(c01, ys, c02 * zs));
    float m1 = fmaf(c01, xs, fmaf(c11, ys, c12 * zs));
    float m2 = fmaf(c02, xs, fmaf(c12, ys, c22 * zs));
    float g  = fmaf(m0, a_c, fmaf(m1, b_c, m2));   // sign of dot(n, xyz), d0>0
    float inv = rsqrtf(fmaf(m0, m0, fmaf(m1, m1, m2 * m2)));
    if (g > 0.0f) inv = -inv;
    if (!(d0 > 0.0f)) inv = 0.0f;                  // where(depth>0, n, 0)
    *nx = m0 * inv; *ny = m1 * inv; *nz = m2 * inv;
}

__global__ __launch_bounds__(128, 2)
void ppal_main(const float* __restrict__ pred, const float* __restrict__ gt,
               double* __restrict__ acc)
{
    const int lane = threadIdx.x;            // 0..63
    const int wy   = threadIdx.y;            // 0..1 (independent sub-band)
    const int j0 = blockIdx.x * 56;
    const int band = blockIdx.y * 2 + wy;    // 0..59
    const int r0 = band * 8;
    const int b  = blockIdx.z;

    const float invFX = 1.0f / 518.857f;
    const float invFY = 1.0f / 519.469f;

    const float* __restrict__ pA = pred + (size_t)b * (HH * WW);
    const float* __restrict__ pB = gt   + (size_t)b * (HH * WW);

    const int c = j0 - 4 + lane;             // owned window column
    const int j = j0 + lane;                 // owned output column
    const bool col_ok = (c >= 0) && (c < WW);
    const bool pix_ok = (lane < 56) && (j < WW);
    const float a  = ((float)c - 319.5f) * invFX;   // column x-weight
    const float a2 = a * a;
    const float ap = ((float)j - 319.5f) * invFX;   // pixel x-weight
    const int ba1 = ((lane + 1) & 63) << 2;
    const int ba2 = ((lane + 2) & 63) << 2;
    const int ba4 = ((lane + 4) & 63) << 2;

    // vertical 8-row sliding sums for own column, both inputs
    float S1A = 0.f, SbA = 0.f, SbbA = 0.f, T1A = 0.f, TbA = 0.f;
    float S1B = 0.f, SbB = 0.f, SbbB = 0.f, T1B = 0.f, TbB = 0.f;

    // ---- warmup: rows r0-4 .. r0+3 (zero-padded OOB) ----
    int off = (r0 - 4) * WW + c;
#pragma unroll
    for (int w = 0; w < 8; ++w) {
        int r = r0 - 4 + w;                  // r <= r0+3 <= 475 < HH always
        bool ok = col_ok && (r >= 0);
        int o = ok ? off : 0;
        float dA = pA[o]; dA = ok ? dA : 0.f;
        float dB = pB[o]; dB = ok ? dB : 0.f;
        float bv = ((float)r - 239.5f) * invFY;
        float bdA = bv * dA, bdB = bv * dB;
        T1A += dA;  TbA += bdA;
        S1A = fmaf(dA,  dA,  S1A);
        SbA = fmaf(bdA, dA,  SbA);
        SbbA = fmaf(bdA, bdA, SbbA);
        T1B += dB;  TbB += bdB;
        S1B = fmaf(dB,  dB,  S1B);
        SbB = fmaf(bdB, dB,  SbB);
        SbbB = fmaf(bdB, bdB, SbbB);
        off += WW;
    }

    // ---- march 8 output rows ----
    float contrib = 0.f;
    int off_new = (r0 + 4) * WW + c;
    int off_old = (r0 - 4) * WW + c;
    int off_ctr = r0 * WW + j;

    for (int s = 0; s < 8; ++s) {
        const int i = r0 + s;
        const bool row_ok = (i < HH);

        // ---- emit pixel (i, j): V holds rows i-4..i+3 ----
        {
            const bool okc = row_ok && pix_ok;
            int o = okc ? off_ctr : 0;
            float d0A = pA[o]; d0A = okc ? d0A : 0.f;
            float d0B = pB[o]; d0B = okc ? d0B : 0.f;
            float bc = ((float)i - 239.5f) * invFY;

            // input A: 9 horizontal box-8 sums -> solve
            float hS1  = box8(S1A,      ba1, ba2, ba4);
            float hSb  = box8(SbA,      ba1, ba2, ba4);
            float hSbb = box8(SbbA,     ba1, ba2, ba4);
            float hT1  = box8(T1A,      ba1, ba2, ba4);
            float hTb  = box8(TbA,      ba1, ba2, ba4);
            float haS1 = box8(a * S1A,  ba1, ba2, ba4);
            float haSb = box8(a * SbA,  ba1, ba2, ba4);
            float haT1 = box8(a * T1A,  ba1, ba2, ba4);
            float ha2S1= box8(a2 * S1A, ba1, ba2, ba4);
            float nA[3];
            solve_normal(ha2S1, haSb, haS1, hSbb, hSb, hS1, haT1, hTb, hT1,
                         ap, bc, d0A, &nA[0], &nA[1], &nA[2]);

            // input B
            float gS1  = box8(S1B,      ba1, ba2, ba4);
            float gSb  = box8(SbB,      ba1, ba2, ba4);
            float gSbb = box8(SbbB,     ba1, ba2, ba4);
            float gT1  = box8(T1B,      ba1, ba2, ba4);
            float gTb  = box8(TbB,      ba1, ba2, ba4);
            float gaS1 = box8(a * S1B,  ba1, ba2, ba4);
            float gaSb = box8(a * SbB,  ba1, ba2, ba4);
            float gaT1 = box8(a * T1B,  ba1, ba2, ba4);
            float ga2S1= box8(a2 * S1B, ba1, ba2, ba4);
            float nB[3];
            solve_normal(ga2S1, gaSb, gaS1, gSbb, gSb, gS1, gaT1, gTb, gT1,
                         ap, bc, d0B, &nB[0], &nB[1], &nB[2]);

            float cp = fabsf(nA[0] - nB[0]) + fabsf(nA[1] - nB[1])
                     + fabsf(nA[2] - nB[2]);
            contrib += okc ? cp : 0.f;
        }

        // ---- slide: row i-4 leaves, row i+4 enters ----
        {
            const bool okn = col_ok && (i + 4 < HH);
            const bool oko = col_ok && (i - 4 >= 0);
            int on = okn ? off_new : 0;
            int oo = oko ? off_old : 0;
            float dnA = pA[on]; dnA = okn ? dnA : 0.f;
            float dnB = pB[on]; dnB = okn ? dnB : 0.f;
            float doA = pA[oo]; doA = oko ? doA : 0.f;
            float doB = pB[oo]; doB = oko ? doB : 0.f;
            float bn = ((float)(i + 4) - 239.5f) * invFY;
            float bo = ((float)(i - 4) - 239.5f) * invFY;
            float bdnA = bn * dnA, bdoA = bo * doA;
            float bdnB = bn * dnB, bdoB = bo * doB;
            T1A += dnA - doA;   TbA += bdnA - bdoA;
            S1A += fmaf(dnA,  dnA,  -doA  * doA);
            SbA += fmaf(bdnA, dnA,  -bdoA * doA);
            SbbA += fmaf(bdnA, bdnA, -bdoA * bdoA);
            T1B += dnB - doB;   TbB += bdnB - bdoB;
            S1B += fmaf(dnB,  dnB,  -doB  * doB);
            SbB += fmaf(bdnB, dnB,  -bdoB * doB);
            SbbB += fmaf(bdnB, bdnB, -bdoB * bdoB);
            off_new += WW; off_old += WW; off_ctr += WW;
        }
    }

    // ---- wave reduce -> ONE plain STORE per wave (no cross-wave sync) ----
    float v = contrib;
#pragma unroll
    for (int o = 32; o > 0; o >>= 1) v += __shfl_down(v, o, 64);
    if (lane == 0) {
        int slot = blockIdx.x + CT * band + (CT * RBAND) * blockIdx.z;
        acc[slot] = (double)v;   // unique slot, written every launch
    }
}

__global__ void ppal_finalize(const double* __restrict__ acc, float* __restrict__ out)
{
    int tid = threadIdx.x;             // 256 threads, one block
    double v = 0.0;
    for (int s = tid; s < NBLK; s += 256) v += acc[s];
#pragma unroll
    for (int off = 32; off > 0; off >>= 1) v += __shfl_down(v, off, 64);
    __shared__ double wsum[4];
    int wid = tid >> 6, lane = tid & 63;
    if (lane == 0) wsum[wid] = v;
    __syncthreads();
    if (tid == 0)
        out[0] = (float)((wsum[0] + wsum[1] + wsum[2] + wsum[3])
                         * (1.0 / 7345944.0));  // mean over B*3*H*W
}

extern "C" void kernel_launch(void* const* d_in, const int* in_sizes, int n_in,
                              void* d_out, int out_size, void* d_ws, size_t ws_size,
                              hipStream_t stream)
{
    const float* pred = (const float*)d_in[0];
    const float* gt   = (const float*)d_in[1];
    float* out  = (float*)d_out;
    double* acc = (double*)d_ws;

    dim3 grid(CT, GY, BATCH);          // 2880 blocks x 2 independent waves
    dim3 block(64, 2);
    ppal_main<<<grid, block, 0, stream>>>(pred, gt, acc);
    ppal_finalize<<<1, 256, 0, stream>>>(acc, out);
}